// Round 1
// baseline (211.388 us; speedup 1.0000x reference)
//
#include <hip/hip_runtime.h>
#include <hip/hip_bf16.h>

#define L_SEQ 2048
#define NH 16
#define DH 64
#define NM 24
#define NCH 32
#define SCALE_F 0.125f
#define EPS_F 1e-4f
#define DN_F 0.35355339059327373f      // sqrt(0.125)
#define HLM_F 1.5890269151739727f      // 0.5*log(24)

typedef __attribute__((ext_vector_type(8))) short short8v;   // 8 bf16 = 4 VGPR (MFMA A/B frag)
typedef __attribute__((ext_vector_type(4))) float f32x4;     // MFMA C/D frag

// round-to-nearest-even f32 -> bf16
__device__ __forceinline__ unsigned short f2bf(float x) {
  unsigned u = __float_as_uint(x);
  u += 0x7FFFu + ((u >> 16) & 1u);
  return (unsigned short)(u >> 16);
}
__device__ __forceinline__ unsigned pk2(float a, float b) {
  return (unsigned)f2bf(a) | ((unsigned)f2bf(b) << 16);
}

// ---------------- K1: f32 features: qdash/kdash (L,24), qnorm/knorm, per-chunk kdash max
__global__ __launch_bounds__(256) void k1_feat(
    const float* __restrict__ qkv, const float* __restrict__ proj,
    float* __restrict__ kdash, float* __restrict__ knorm,
    float* __restrict__ qdash, float* __restrict__ qnorm,
    float* __restrict__ pmax)
{
  __shared__ float sP[24][64];
  __shared__ float sX[64][65];
  __shared__ float sRed[256];
  const int c = blockIdx.x, h = blockIdx.y, t = threadIdx.x;
  for (int i = t; i < 24 * 64; i += 256) sP[i >> 6][i & 63] = proj[i];
  float lmax = -1e30f;
  const int r = t >> 2, mg = t & 3;
  for (int qk = 0; qk < 2; ++qk) {
    const int slot = qk ? 0 : 1;   // first K (slot1), then Q (slot0)
    __syncthreads();
    for (int i = t; i < 4096; i += 256) {
      int rr = i >> 6, d = i & 63;
      int l = c * 64 + rr;
      sX[rr][d] = qkv[(((size_t)l * 3 + slot) * NH + h) * DH + d];
    }
    __syncthreads();
    float acc[6] = {0.f, 0.f, 0.f, 0.f, 0.f, 0.f};
    float sq = 0.f;
    for (int d = 0; d < 64; ++d) {
      float x = sX[r][d];
#pragma unroll
      for (int i = 0; i < 6; ++i) acc[i] += x * sP[mg * 6 + i][d];
      sq += x * x;
    }
    int l = c * 64 + r;
    float* dsh = qk ? qdash : kdash;
#pragma unroll
    for (int i = 0; i < 6; ++i) {
      float v = acc[i] * DN_F;
      dsh[((size_t)h * L_SEQ + l) * 24 + mg * 6 + i] = v;
      if (!qk) lmax = fmaxf(lmax, v);
    }
    if (mg == 0) (qk ? qnorm : knorm)[h * L_SEQ + l] = 0.5f * SCALE_F * sq;
  }
  sRed[t] = lmax;
  __syncthreads();
#pragma unroll
  for (int s = 128; s > 0; s >>= 1) {
    if (t < s) sRed[t] = fmaxf(sRed[t], sRed[t + s]);
    __syncthreads();
  }
  if (t == 0) pmax[h * 32 + c] = sRed[0];
}

// ---------------- K2: per-head stabilizer = max over chunks
__global__ void k2_stab(const float* __restrict__ pmax, float* __restrict__ stabk)
{
  int h = blockIdx.x, t = threadIdx.x;  // 64 threads
  float v = (t < 32) ? pmax[h * 32 + t] : -1e30f;
#pragma unroll
  for (int m = 16; m; m >>= 1) v = fmaxf(v, __shfl_xor(v, m));
  if (t == 0) stabk[h] = v;
}

// ---------------- K3: k' (bf16 padded to 32), in-chunk prefix kpfx (f32), chunk k'(x)v sums (f32)
__global__ __launch_bounds__(256) void k3_kprime(
    const float* __restrict__ qkv, const float* __restrict__ kdash,
    const float* __restrict__ knorm, const float* __restrict__ stabk,
    unsigned* __restrict__ kpw, float* __restrict__ kpfx, float* __restrict__ kvs)
{
  __shared__ float sKp[64][25];
  __shared__ float sV[64][65];
  const int c = blockIdx.x, h = blockIdx.y, t = threadIdx.x;
  const float stab = stabk[h];
  for (int i = t; i < 4096; i += 256) {
    int r = i >> 6, d = i & 63;
    int l = c * 64 + r;
    sV[r][d] = qkv[(((size_t)l * 3 + 2) * NH + h) * DH + d];
  }
  for (int i = t; i < 1536; i += 256) {
    int r = i / 24, m = i % 24;
    int l = c * 64 + r;
    sKp[r][m] = __expf(kdash[((size_t)h * L_SEQ + l) * 24 + m] - knorm[h * L_SEQ + l] - stab) + EPS_F;
  }
  __syncthreads();
  for (int w = t; w < 1024; w += 256) {   // write kp bf16, m padded to 32 with zeros
    int r = w >> 4, wo = w & 15;
    int l = c * 64 + r;
    float a = (wo < 12) ? sKp[r][2 * wo] : 0.f;
    float bb = (wo < 12) ? sKp[r][2 * wo + 1] : 0.f;
    kpw[((size_t)h * L_SEQ + l) * 16 + wo] = pk2(a, bb);
  }
  float acc[6] = {0.f, 0.f, 0.f, 0.f, 0.f, 0.f};
  for (int r2 = 0; r2 < 64; ++r2) {
#pragma unroll
    for (int i = 0; i < 6; ++i) {
      int e = t * 6 + i;
      acc[i] += sKp[r2][e >> 6] * sV[r2][e & 63];
    }
  }
#pragma unroll
  for (int i = 0; i < 6; ++i)
    kvs[((size_t)h * NCH + c) * 1536 + t * 6 + i] = acc[i];
  if (t < 24) {
    float run = 0.f;
    for (int r2 = 0; r2 < 64; ++r2) {
      run += sKp[r2][t];
      kpfx[((size_t)h * L_SEQ + c * 64 + r2) * 24 + t] = run;
    }
  }
}

// ---------------- K4: V -> blocked transposed bf16  vt[h][chunk][d][64 cols l]
__global__ __launch_bounds__(256) void k4_vt(const float* __restrict__ qkv, unsigned* __restrict__ vtw)
{
  __shared__ float sV[64][65];
  const int c = blockIdx.x, h = blockIdx.y, t = threadIdx.x;
  for (int i = t; i < 4096; i += 256) {
    int r = i >> 6, d = i & 63;
    int l = c * 64 + r;
    sV[r][d] = qkv[(((size_t)l * 3 + 2) * NH + h) * DH + d];
  }
  __syncthreads();
  for (int w = t; w < 2048; w += 256) {
    int d = w >> 5, lp = w & 31;
    vtw[((size_t)h * NCH + c) * 2048 + d * 32 + lp] = pk2(sV[2 * lp][d], sV[2 * lp + 1][d]);
  }
}

// ---------------- K5: exclusive prefixes over chunks: KVexcl^T bf16 [h][b][d][32m], kcum-excl f32
__global__ __launch_bounds__(256) void k5_prefix(
    const float* __restrict__ kvs, const float* __restrict__ kpfx,
    unsigned* __restrict__ kvxt, float* __restrict__ kcumx)
{
  const int h = blockIdx.x, t = threadIdx.x;
  float run[4][2] = {{0.f,0.f},{0.f,0.f},{0.f,0.f},{0.f,0.f}};
  float runk = 0.f;
  for (int b = 0; b < 32; ++b) {
#pragma unroll
    for (int i = 0; i < 4; ++i) {
      int p = t * 4 + i;          // p = d*16 + mp
      int d = p >> 4, mp = p & 15;
      int m0 = 2 * mp, m1 = 2 * mp + 1;
      float a = (m0 < 24) ? run[i][0] : 0.f;
      float bb = (m1 < 24) ? run[i][1] : 0.f;
      kvxt[((size_t)h * NCH + b) * 1024 + p] = pk2(a, bb);
      if (m0 < 24) run[i][0] += kvs[((size_t)h * NCH + b) * 1536 + m0 * 64 + d];
      if (m1 < 24) run[i][1] += kvs[((size_t)h * NCH + b) * 1536 + m1 * 64 + d];
    }
    if (t < 24) {
      kcumx[((size_t)h * NCH + b) * 24 + t] = runk;
      runk += kpfx[((size_t)h * L_SEQ + b * 64 + 63) * 24 + t];
    }
  }
}

// ---------------- K6: fused banded + performer attention, one block per (h, 64-row chunk)
__global__ __launch_bounds__(256, 2) void k6_attn(
    const float* __restrict__ qkv, const unsigned* __restrict__ kpw,
    const float* __restrict__ kpfx, const float* __restrict__ kcumx,
    const unsigned* __restrict__ vtw, const unsigned* __restrict__ kvxt,
    const float* __restrict__ qdash, const float* __restrict__ qnorm,
    const float* __restrict__ stabk, float* __restrict__ out)
{
  __shared__ __attribute__((aligned(16))) char lds[56064];
  char* sKW = lds;                       // [192][64]b16 K tiles; later W [64][192]b16 (24576 B)
  char* sKp = lds + 24576;               // [192][32]b16 k'; later KVexcl^T [64][32]b16 (12288 B)
  char* sQV = lds + 36864;               // [64][64]b16 Q; later V^T tile (8192 B)
  char* sQp = lds + 45056;               // [64][32]b16 q' (4096 B)
  float* sQpF = (float*)(lds + 49152);   // [64][24] f32 q' for stats (6144 B)
  float* sSum = (float*)(lds + 55296);   // sumexp[64]
  float* sGps = sSum + 64;
  float* sRin = sGps + 64;

  const int b = blockIdx.x, h = blockIdx.y, t = threadIdx.x;
  const int wv = t >> 6, lane = t & 63, g = lane >> 4, ln = lane & 15;
  const int keybase = b * 64 - 128;
  const int jmin = (b >= 2) ? 0 : (128 - 64 * b);
  const int rA = wv * 16 + ln;   // A-frag row (query row owned by this wave's m-tile)

  // ---- stage K (192 rows, f32->bf16, XOR swizzled rows) ----
  for (int w = t; w < 6144; w += 256) {
    int r = w >> 5, dp = w & 31;
    int l = keybase + r; l = l < 0 ? 0 : l;
    const float* s = qkv + (((size_t)l * 3 + 1) * NH + h) * DH + dp * 2;
    *(unsigned*)(sKW + (r * 128 + (((dp * 4)) ^ ((r & 7) << 4)))) = pk2(s[0], s[1]);
  }
  // ---- stage Q ----
  for (int w = t; w < 2048; w += 256) {
    int r = w >> 5, dp = w & 31;
    int l = b * 64 + r;
    const float* s = qkv + (((size_t)l * 3 + 0) * NH + h) * DH + dp * 2;
    *(unsigned*)(sQV + (r * 128 + (((dp * 4)) ^ ((r & 7) << 4)))) = pk2(s[0], s[1]);
  }
  // ---- stage k' (bf16, already padded to 32) ----
  for (int w = t; w < 3072; w += 256) {
    int r = w >> 4, wo = w & 15;
    int l = keybase + r; l = l < 0 ? 0 : l;
    *(unsigned*)(sKp + (r * 64 + (((wo * 4)) ^ ((r & 3) << 4)))) = kpw[((size_t)h * L_SEQ + l) * 16 + wo];
  }
  // ---- q' per row (f32 stats copy + bf16 frag copy) ----
  float qlog = 0.f;
  if (t < 64) {
    int r = t, l = b * 64 + r;
    const float* qdp = qdash + ((size_t)h * L_SEQ + l) * 24;
    float qd[24], mx = -1e30f;
#pragma unroll
    for (int m = 0; m < 24; ++m) { qd[m] = qdp[m]; mx = fmaxf(mx, qd[m]); }
    float qpv[24];
#pragma unroll
    for (int m = 0; m < 24; ++m) { qpv[m] = __expf(qd[m] - mx) + EPS_F; sQpF[r * 24 + m] = qpv[m]; }
    qlog = mx - qnorm[h * L_SEQ + l] - HLM_F;
#pragma unroll
    for (int wo = 0; wo < 16; ++wo) {
      float a = (wo < 12) ? qpv[2 * wo] : 0.f;
      float bb = (wo < 12) ? qpv[2 * wo + 1] : 0.f;
      *(unsigned*)(sQp + (r * 64 + (((wo * 4)) ^ ((r & 3) << 4)))) = pk2(a, bb);
    }
  }
  __syncthreads();

  // ---- S = Q K^T (masked exp), wave-local row sums ----
  float eF[12][4];
  float rs[4] = {0.f, 0.f, 0.f, 0.f};
  short8v aS0 = *(const short8v*)(sQV + (rA * 128 + ((g * 16) ^ ((rA & 7) << 4))));
  short8v aS1 = *(const short8v*)(sQV + (rA * 128 + ((64 + g * 16) ^ ((rA & 7) << 4))));
#pragma unroll
  for (int nt = 0; nt < 12; ++nt) {
    int rB = nt * 16 + ln;
    short8v b0 = *(const short8v*)(sKW + (rB * 128 + ((g * 16) ^ ((rB & 7) << 4))));
    short8v b1 = *(const short8v*)(sKW + (rB * 128 + ((64 + g * 16) ^ ((rB & 7) << 4))));
    f32x4 acc = {0.f, 0.f, 0.f, 0.f};
    acc = __builtin_amdgcn_mfma_f32_16x16x32_bf16(aS0, b0, acc, 0, 0, 0);
    acc = __builtin_amdgcn_mfma_f32_16x16x32_bf16(aS1, b1, acc, 0, 0, 0);
    int j = nt * 16 + ln;
#pragma unroll
    for (int reg = 0; reg < 4; ++reg) {
      int rl = wv * 16 + g * 4 + reg;
      float e = 0.f;
      if (j >= rl && j <= rl + 128 && j >= jmin) e = __expf(SCALE_F * acc[reg]);
      eF[nt][reg] = e;
      rs[reg] += e;
    }
  }
#pragma unroll
  for (int reg = 0; reg < 4; ++reg) {
    float v = rs[reg];
    v += __shfl_xor(v, 1); v += __shfl_xor(v, 2);
    v += __shfl_xor(v, 4); v += __shfl_xor(v, 8);
    if (ln == 0) sSum[wv * 16 + g * 4 + reg] = v;
  }

  // ---- P = q' k'^T ----
  float pF[12][4];
  short8v aP = *(const short8v*)(sQp + (rA * 64 + ((g * 16) ^ ((rA & 3) << 4))));
#pragma unroll
  for (int nt = 0; nt < 12; ++nt) {
    int rB = nt * 16 + ln;
    short8v bp = *(const short8v*)(sKp + (rB * 64 + ((g * 16) ^ ((rB & 3) << 4))));
    f32x4 acc = {0.f, 0.f, 0.f, 0.f};
    acc = __builtin_amdgcn_mfma_f32_16x16x32_bf16(aP, bp, acc, 0, 0, 0);
#pragma unroll
    for (int reg = 0; reg < 4; ++reg) pF[nt][reg] = acc[reg];
  }
  __syncthreads();

  // ---- per-row stats (f32, via k' prefix sums) ----
  if (t < 64) {
    int r = t, l = b * 64 + r;
    const float* kfc = kpfx + ((size_t)h * L_SEQ + l) * 24;
    const float* kcx = kcumx + ((size_t)h * NCH + b) * 24;
    int b1i = (b >= 1) ? b - 1 : 0;
    int b2i = (b >= 2) ? b - 2 : 0;
    int rm1 = (r >= 1) ? r - 1 : 0;
    const float* T1p = kpfx + ((size_t)h * L_SEQ + b1i * 64 + 63) * 24;
    const float* T2p = kpfx + ((size_t)h * L_SEQ + b2i * 64 + 63) * 24;
    const float* S2p = kpfx + ((size_t)h * L_SEQ + b2i * 64 + rm1) * 24;
    float f1 = (b >= 1) ? 1.f : 0.f;
    float f2 = (b >= 2) ? 1.f : 0.f;
    float fr = (b >= 2 && r >= 1) ? 1.f : 0.f;
    float psc = 0.f, kcs = 0.f, bnd = 0.f;
#pragma unroll
    for (int m = 0; m < 24; ++m) {
      float qp = sQpF[r * 24 + m];
      float kc = kfc[m];
      psc += qp * kc;
      kcs += qp * kcx[m];
      bnd += qp * (kc + f1 * T1p[m] + f2 * T2p[m] - fr * S2p[m]);
    }
    float goc = kcs + psc;            // global_out_cumsum
    float gqk = SCALE_F * bnd;        // gqk_sum
    float se = sSum[r];
    float lse = __logf(se);           // qk_lse over band
    float gscale = qlog + stabk[h] - HLM_F;
    float gln = __logf(fmaxf(goc - gqk, 1e-24f)) + gscale;
    float mx2 = fmaxf(lse, gln), mn2 = fminf(lse, gln);
    float lognorm = mx2 + log1pf(__expf(mn2 - mx2));
    sGps[r] = __expf(gscale - lognorm);
    sRin[r] = 1.f / se;
  }
  __syncthreads();

  // ---- form W (bf16) into old K region ----
  float gpr[4], rin[4];
#pragma unroll
  for (int reg = 0; reg < 4; ++reg) {
    int rl = wv * 16 + g * 4 + reg;
    gpr[reg] = sGps[rl];
    rin[reg] = sRin[rl];
  }
#pragma unroll
  for (int nt = 0; nt < 12; ++nt) {
    int j = nt * 16 + ln;
#pragma unroll
    for (int reg = 0; reg < 4; ++reg) {
      int rl = wv * 16 + g * 4 + reg;
      bool causal = (j >= 128) && (j <= 128 + rl);
      bool bprev = (j >= rl) && (j < 128) && (j >= jmin);
      float coef = causal ? (1.f - SCALE_F) * gpr[reg] : (bprev ? -SCALE_F * gpr[reg] : 0.f);
      float wgt = eF[nt][reg] * rin[reg] + coef * pF[nt][reg];
      float wn = __shfl_xor(wgt, 1);
      if ((ln & 1) == 0) {
        *(unsigned*)(sKW + (rl * 384 + ((j * 2) ^ ((rl & 7) << 4)))) = pk2(wgt, wn);
      }
    }
  }
  __syncthreads();

  // ---- O1 = W * V (192-K), V^T tiles staged per 64 cols ----
  f32x4 oF[4];
#pragma unroll
  for (int dt = 0; dt < 4; ++dt) { f32x4 z = {0.f, 0.f, 0.f, 0.f}; oF[dt] = z; }
  for (int vt3 = 0; vt3 < 3; ++vt3) {
    int lt = b - 2 + vt3; lt = lt < 0 ? 0 : lt;
    for (int w = t; w < 2048; w += 256) {
      int d = w >> 5, jp = w & 31;
      *(unsigned*)(sQV + (d * 128 + ((jp * 4) ^ ((d & 7) << 4)))) = vtw[((size_t)h * NCH + lt) * 2048 + d * 32 + jp];
    }
    __syncthreads();
#pragma unroll
    for (int ks = 0; ks < 2; ++ks) {
      short8v aw = *(const short8v*)(sKW + (rA * 384 + ((vt3 * 128 + ks * 64 + g * 16) ^ ((rA & 7) << 4))));
#pragma unroll
      for (int dt = 0; dt < 4; ++dt) {
        int rB = dt * 16 + ln;
        short8v bv = *(const short8v*)(sQV + (rB * 128 + ((ks * 64 + g * 16) ^ ((rB & 7) << 4))));
        oF[dt] = __builtin_amdgcn_mfma_f32_16x16x32_bf16(aw, bv, oF[dt], 0, 0, 0);
      }
    }
    __syncthreads();
  }

  // ---- Og = q' * KVexcl ----
  for (int w = t; w < 1024; w += 256) {
    int d = w >> 4, mp = w & 15;
    *(unsigned*)(sKp + (d * 64 + ((mp * 4) ^ ((d & 3) << 4)))) = kvxt[((size_t)h * NCH + b) * 1024 + w];
  }
  __syncthreads();
  short8v aq = *(const short8v*)(sQp + (rA * 64 + ((g * 16) ^ ((rA & 3) << 4))));
  f32x4 ogF[4];
#pragma unroll
  for (int dt = 0; dt < 4; ++dt) {
    int rB = dt * 16 + ln;
    short8v bg = *(const short8v*)(sKp + (rB * 64 + ((g * 16) ^ ((rB & 3) << 4))));
    f32x4 z = {0.f, 0.f, 0.f, 0.f};
    ogF[dt] = __builtin_amdgcn_mfma_f32_16x16x32_bf16(aq, bg, z, 0, 0, 0);
  }

  // ---- epilogue: out = O1 + gps * Og ----
#pragma unroll
  for (int dt = 0; dt < 4; ++dt) {
    int d = dt * 16 + ln;
#pragma unroll
    for (int reg = 0; reg < 4; ++reg) {
      int rl = wv * 16 + g * 4 + reg;
      int l = b * 64 + rl;
      out[((size_t)l * NH + h) * DH + d] = oF[dt][reg] + gpr[reg] * ogF[dt][reg];
    }
  }
}

extern "C" void kernel_launch(void* const* d_in, const int* in_sizes, int n_in,
                              void* d_out, int out_size, void* d_ws, size_t ws_size,
                              hipStream_t stream)
{
  const float* qkv = (const float*)d_in[0];
  const float* proj = (const float*)d_in[1];
  float* out = (float*)d_out;
  char* ws = (char*)d_ws;

  float* kdash   = (float*)(ws + 0);           // 3145728
  float* qdash   = (float*)(ws + 3145728);     // 3145728
  float* knorm   = (float*)(ws + 6291456);     // 131072
  float* qnorm   = (float*)(ws + 6422528);     // 131072
  float* pmax    = (float*)(ws + 6553600);     // 2048
  float* stabk   = (float*)(ws + 6555648);     // 64
  unsigned* kpw  = (unsigned*)(ws + 6556672);  // 2097152 (bf16 [H][L][32])
  float* kpfx    = (float*)(ws + 8653824);     // 3145728
  unsigned* vtw  = (unsigned*)(ws + 11799552); // 4194304 (bf16 [H][32][64][64])
  float* kvs     = (float*)(ws + 15993856);    // 3145728
  unsigned* kvxt = (unsigned*)(ws + 19139584); // 2097152 (bf16 [H][32][64][32])
  float* kcumx   = (float*)(ws + 21236736);    // 49152   (ends at 21285888)

  k1_feat<<<dim3(32, 16), 256, 0, stream>>>(qkv, proj, kdash, knorm, qdash, qnorm, pmax);
  k2_stab<<<16, 64, 0, stream>>>(pmax, stabk);
  k3_kprime<<<dim3(32, 16), 256, 0, stream>>>(qkv, kdash, knorm, stabk, kpw, kpfx, kvs);
  k4_vt<<<dim3(32, 16), 256, 0, stream>>>(qkv, vtw);
  k5_prefix<<<16, 256, 0, stream>>>(kvs, kpfx, kvxt, kcumx);
  k6_attn<<<dim3(32, 16), 256, 0, stream>>>(qkv, kpw, kpfx, kcumx, vtw, kvxt, qdash, qnorm, stabk, out);
}

// Round 2
// 147.235 us; speedup vs baseline: 1.4357x; 1.4357x over previous
//
#include <hip/hip_runtime.h>
#include <hip/hip_bf16.h>

#define L_SEQ 2048
#define NH 16
#define DH 64
#define NM 24
#define NCH 32
#define SCALE_F 0.125f
#define EPS_F 1e-4f
#define DN_F 0.35355339059327373f      // sqrt(0.125)
#define HLM_F 1.5890269151739727f      // 0.5*log(24)

typedef __attribute__((ext_vector_type(8))) short short8v;   // 8 bf16 = 4 VGPR (MFMA A/B frag)
typedef __attribute__((ext_vector_type(4))) float f32x4;     // MFMA C/D frag

// round-to-nearest-even f32 -> bf16
__device__ __forceinline__ unsigned short f2bf(float x) {
  unsigned u = __float_as_uint(x);
  u += 0x7FFFu + ((u >> 16) & 1u);
  return (unsigned short)(u >> 16);
}
__device__ __forceinline__ unsigned pk2(float a, float b) {
  return (unsigned)f2bf(a) | ((unsigned)f2bf(b) << 16);
}

// ---------------- K1: f32 features: qdash/kdash (L,24), qnorm/knorm, per-chunk kdash max
__global__ __launch_bounds__(256) void k1_feat(
    const float* __restrict__ qkv, const float* __restrict__ proj,
    float* __restrict__ kdash, float* __restrict__ knorm,
    float* __restrict__ qdash, float* __restrict__ qnorm,
    float* __restrict__ pmax)
{
  __shared__ float sP[24][64];
  __shared__ float sX[64][65];
  __shared__ float sRed[256];
  const int c = blockIdx.x, h = blockIdx.y, t = threadIdx.x;
  for (int i = t; i < 24 * 64; i += 256) sP[i >> 6][i & 63] = proj[i];
  float lmax = -1e30f;
  const int r = t >> 2, mg = t & 3;
  for (int qk = 0; qk < 2; ++qk) {
    const int slot = qk ? 0 : 1;   // first K (slot1), then Q (slot0)
    __syncthreads();
    for (int i = t; i < 4096; i += 256) {
      int rr = i >> 6, d = i & 63;
      int l = c * 64 + rr;
      sX[rr][d] = qkv[(((size_t)l * 3 + slot) * NH + h) * DH + d];
    }
    __syncthreads();
    float acc[6] = {0.f, 0.f, 0.f, 0.f, 0.f, 0.f};
    float sq = 0.f;
    for (int d = 0; d < 64; ++d) {
      float x = sX[r][d];
#pragma unroll
      for (int i = 0; i < 6; ++i) acc[i] += x * sP[mg * 6 + i][d];
      sq += x * x;
    }
    int l = c * 64 + r;
    float* dsh = qk ? qdash : kdash;
#pragma unroll
    for (int i = 0; i < 6; ++i) {
      float v = acc[i] * DN_F;
      dsh[((size_t)h * L_SEQ + l) * 24 + mg * 6 + i] = v;
      if (!qk) lmax = fmaxf(lmax, v);
    }
    if (mg == 0) (qk ? qnorm : knorm)[h * L_SEQ + l] = 0.5f * SCALE_F * sq;
  }
  sRed[t] = lmax;
  __syncthreads();
#pragma unroll
  for (int s = 128; s > 0; s >>= 1) {
    if (t < s) sRed[t] = fmaxf(sRed[t], sRed[t + s]);
    __syncthreads();
  }
  if (t == 0) pmax[h * 32 + c] = sRed[0];
}

// ---------------- K2: per-head stabilizer = max over chunks
__global__ void k2_stab(const float* __restrict__ pmax, float* __restrict__ stabk)
{
  int h = blockIdx.x, t = threadIdx.x;  // 64 threads
  float v = (t < 32) ? pmax[h * 32 + t] : -1e30f;
#pragma unroll
  for (int m = 16; m; m >>= 1) v = fmaxf(v, __shfl_xor(v, m));
  if (t == 0) stabk[h] = v;
}

// ---------------- K3: k' (bf16 padded to 32), in-chunk prefix kpfx (f32), chunk k'(x)v sums (f32),
//                   plus V -> blocked transposed bf16 vt[h][chunk][d][64 cols l] (folded former K4)
__global__ __launch_bounds__(256) void k3_kprime(
    const float* __restrict__ qkv, const float* __restrict__ kdash,
    const float* __restrict__ knorm, const float* __restrict__ stabk,
    unsigned* __restrict__ kpw, float* __restrict__ kpfx, float* __restrict__ kvs,
    unsigned* __restrict__ vtw)
{
  __shared__ float sKp[64][25];
  __shared__ float sV[64][65];
  const int c = blockIdx.x, h = blockIdx.y, t = threadIdx.x;
  const float stab = stabk[h];
  for (int i = t; i < 4096; i += 256) {
    int r = i >> 6, d = i & 63;
    int l = c * 64 + r;
    sV[r][d] = qkv[(((size_t)l * 3 + 2) * NH + h) * DH + d];
  }
  for (int i = t; i < 1536; i += 256) {
    int r = i / 24, m = i % 24;
    int l = c * 64 + r;
    sKp[r][m] = __expf(kdash[((size_t)h * L_SEQ + l) * 24 + m] - knorm[h * L_SEQ + l] - stab) + EPS_F;
  }
  __syncthreads();
  for (int w = t; w < 1024; w += 256) {   // write kp bf16, m padded to 32 with zeros
    int r = w >> 4, wo = w & 15;
    int l = c * 64 + r;
    float a = (wo < 12) ? sKp[r][2 * wo] : 0.f;
    float bb = (wo < 12) ? sKp[r][2 * wo + 1] : 0.f;
    kpw[((size_t)h * L_SEQ + l) * 16 + wo] = pk2(a, bb);
  }
  // folded K4: V transpose to bf16 blocked layout
  for (int w = t; w < 2048; w += 256) {
    int d = w >> 5, lp = w & 31;
    vtw[((size_t)h * NCH + c) * 2048 + d * 32 + lp] = pk2(sV[2 * lp][d], sV[2 * lp + 1][d]);
  }
  float acc[6] = {0.f, 0.f, 0.f, 0.f, 0.f, 0.f};
  for (int r2 = 0; r2 < 64; ++r2) {
#pragma unroll
    for (int i = 0; i < 6; ++i) {
      int e = t * 6 + i;
      acc[i] += sKp[r2][e >> 6] * sV[r2][e & 63];
    }
  }
#pragma unroll
  for (int i = 0; i < 6; ++i)
    kvs[((size_t)h * NCH + c) * 1536 + t * 6 + i] = acc[i];
  if (t < 24) {
    float run = 0.f;
    for (int r2 = 0; r2 < 64; ++r2) {
      run += sKp[r2][t];
      kpfx[((size_t)h * L_SEQ + c * 64 + r2) * 24 + t] = run;
    }
  }
}

// ---------------- K5: exclusive prefixes over chunks, block per (h, b):
//                   KVexcl^T bf16 [h][b][d][32m], kcum-excl f32.
//                   Redundant-recompute scan: block (h,b) sums kvs[h][0..b-1] coalesced.
__global__ __launch_bounds__(256) void k5_prefix(
    const float* __restrict__ kvs, const float* __restrict__ kpfx,
    unsigned* __restrict__ kvxt, float* __restrict__ kcumx)
{
  __shared__ float sS[1536];
  const int b = blockIdx.x, h = blockIdx.y, t = threadIdx.x;
  float acc[6] = {0.f, 0.f, 0.f, 0.f, 0.f, 0.f};
  for (int bp = 0; bp < b; ++bp) {
    const float* src = kvs + ((size_t)h * NCH + bp) * 1536;
#pragma unroll
    for (int j = 0; j < 6; ++j) acc[j] += src[t + j * 256];
  }
#pragma unroll
  for (int j = 0; j < 6; ++j) sS[t + j * 256] = acc[j];
  if (t < 24) {
    float runk = 0.f;
    for (int bp = 0; bp < b; ++bp)
      runk += kpfx[((size_t)h * L_SEQ + bp * 64 + 63) * 24 + t];
    kcumx[((size_t)h * NCH + b) * 24 + t] = runk;
  }
  __syncthreads();
  for (int w = t; w < 1024; w += 256) {
    int d = w >> 4, mp = w & 15;
    int m0 = 2 * mp, m1 = m0 + 1;
    float a = (m0 < 24) ? sS[m0 * 64 + d] : 0.f;
    float bb = (m1 < 24) ? sS[m1 * 64 + d] : 0.f;
    kvxt[((size_t)h * NCH + b) * 1024 + w] = pk2(a, bb);
  }
}

// ---------------- K6: fused banded + performer attention, one block per (h, 64-row chunk)
__global__ __launch_bounds__(256, 2) void k6_attn(
    const float* __restrict__ qkv, const unsigned* __restrict__ kpw,
    const float* __restrict__ kpfx, const float* __restrict__ kcumx,
    const unsigned* __restrict__ vtw, const unsigned* __restrict__ kvxt,
    const float* __restrict__ qdash, const float* __restrict__ qnorm,
    const float* __restrict__ stabk, float* __restrict__ out)
{
  __shared__ __attribute__((aligned(16))) char lds[56064];
  char* sKW = lds;                       // [192][64]b16 K tiles; later W [64][192]b16 (24576 B)
  char* sKp = lds + 24576;               // [192][32]b16 k'; later KVexcl^T [64][32]b16 (12288 B)
  char* sQV = lds + 36864;               // [64][64]b16 Q; later V^T tile (8192 B)
  char* sQp = lds + 45056;               // [64][32]b16 q' (4096 B)
  float* sQpF = (float*)(lds + 49152);   // [64][24] f32 q' for stats (6144 B)
  float* sSum = (float*)(lds + 55296);   // sumexp[64]
  float* sGps = sSum + 64;
  float* sRin = sGps + 64;

  const int b = blockIdx.x, h = blockIdx.y, t = threadIdx.x;
  const int wv = t >> 6, lane = t & 63, g = lane >> 4, ln = lane & 15;
  const int keybase = b * 64 - 128;
  const int jmin = (b >= 2) ? 0 : (128 - 64 * b);
  const int rA = wv * 16 + ln;   // A-frag row (query row owned by this wave's m-tile)

  // ---- stage K (192 rows, f32->bf16, XOR swizzled rows) ----
  for (int w = t; w < 6144; w += 256) {
    int r = w >> 5, dp = w & 31;
    int l = keybase + r; l = l < 0 ? 0 : l;
    const float* s = qkv + (((size_t)l * 3 + 1) * NH + h) * DH + dp * 2;
    *(unsigned*)(sKW + (r * 128 + (((dp * 4)) ^ ((r & 7) << 4)))) = pk2(s[0], s[1]);
  }
  // ---- stage Q ----
  for (int w = t; w < 2048; w += 256) {
    int r = w >> 5, dp = w & 31;
    int l = b * 64 + r;
    const float* s = qkv + (((size_t)l * 3 + 0) * NH + h) * DH + dp * 2;
    *(unsigned*)(sQV + (r * 128 + (((dp * 4)) ^ ((r & 7) << 4)))) = pk2(s[0], s[1]);
  }
  // ---- stage k' (bf16, already padded to 32) ----
  for (int w = t; w < 3072; w += 256) {
    int r = w >> 4, wo = w & 15;
    int l = keybase + r; l = l < 0 ? 0 : l;
    *(unsigned*)(sKp + (r * 64 + (((wo * 4)) ^ ((r & 3) << 4)))) = kpw[((size_t)h * L_SEQ + l) * 16 + wo];
  }
  // ---- q' per row (f32 stats copy + bf16 frag copy) ----
  float qlog = 0.f;
  if (t < 64) {
    int r = t, l = b * 64 + r;
    const float* qdp = qdash + ((size_t)h * L_SEQ + l) * 24;
    float qd[24], mx = -1e30f;
#pragma unroll
    for (int m = 0; m < 24; ++m) { qd[m] = qdp[m]; mx = fmaxf(mx, qd[m]); }
    float qpv[24];
#pragma unroll
    for (int m = 0; m < 24; ++m) { qpv[m] = __expf(qd[m] - mx) + EPS_F; sQpF[r * 24 + m] = qpv[m]; }
    qlog = mx - qnorm[h * L_SEQ + l] - HLM_F;
#pragma unroll
    for (int wo = 0; wo < 16; ++wo) {
      float a = (wo < 12) ? qpv[2 * wo] : 0.f;
      float bb = (wo < 12) ? qpv[2 * wo + 1] : 0.f;
      *(unsigned*)(sQp + (r * 64 + (((wo * 4)) ^ ((r & 3) << 4)))) = pk2(a, bb);
    }
  }
  __syncthreads();

  // ---- S = Q K^T (masked exp), wave-local row sums ----
  float eF[12][4];
  float rs[4] = {0.f, 0.f, 0.f, 0.f};
  short8v aS0 = *(const short8v*)(sQV + (rA * 128 + ((g * 16) ^ ((rA & 7) << 4))));
  short8v aS1 = *(const short8v*)(sQV + (rA * 128 + ((64 + g * 16) ^ ((rA & 7) << 4))));
#pragma unroll
  for (int nt = 0; nt < 12; ++nt) {
    int rB = nt * 16 + ln;
    short8v b0 = *(const short8v*)(sKW + (rB * 128 + ((g * 16) ^ ((rB & 7) << 4))));
    short8v b1 = *(const short8v*)(sKW + (rB * 128 + ((64 + g * 16) ^ ((rB & 7) << 4))));
    f32x4 acc = {0.f, 0.f, 0.f, 0.f};
    acc = __builtin_amdgcn_mfma_f32_16x16x32_bf16(aS0, b0, acc, 0, 0, 0);
    acc = __builtin_amdgcn_mfma_f32_16x16x32_bf16(aS1, b1, acc, 0, 0, 0);
    int j = nt * 16 + ln;
#pragma unroll
    for (int reg = 0; reg < 4; ++reg) {
      int rl = wv * 16 + g * 4 + reg;
      float e = 0.f;
      if (j >= rl && j <= rl + 128 && j >= jmin) e = __expf(SCALE_F * acc[reg]);
      eF[nt][reg] = e;
      rs[reg] += e;
    }
  }
#pragma unroll
  for (int reg = 0; reg < 4; ++reg) {
    float v = rs[reg];
    v += __shfl_xor(v, 1); v += __shfl_xor(v, 2);
    v += __shfl_xor(v, 4); v += __shfl_xor(v, 8);
    if (ln == 0) sSum[wv * 16 + g * 4 + reg] = v;
  }

  // ---- P = q' k'^T ----
  float pF[12][4];
  short8v aP = *(const short8v*)(sQp + (rA * 64 + ((g * 16) ^ ((rA & 3) << 4))));
#pragma unroll
  for (int nt = 0; nt < 12; ++nt) {
    int rB = nt * 16 + ln;
    short8v bp = *(const short8v*)(sKp + (rB * 64 + ((g * 16) ^ ((rB & 3) << 4))));
    f32x4 acc = {0.f, 0.f, 0.f, 0.f};
    acc = __builtin_amdgcn_mfma_f32_16x16x32_bf16(aP, bp, acc, 0, 0, 0);
#pragma unroll
    for (int reg = 0; reg < 4; ++reg) pF[nt][reg] = acc[reg];
  }
  __syncthreads();

  // ---- per-row stats (f32, via k' prefix sums) ----
  if (t < 64) {
    int r = t, l = b * 64 + r;
    const float* kfc = kpfx + ((size_t)h * L_SEQ + l) * 24;
    const float* kcx = kcumx + ((size_t)h * NCH + b) * 24;
    int b1i = (b >= 1) ? b - 1 : 0;
    int b2i = (b >= 2) ? b - 2 : 0;
    int rm1 = (r >= 1) ? r - 1 : 0;
    const float* T1p = kpfx + ((size_t)h * L_SEQ + b1i * 64 + 63) * 24;
    const float* T2p = kpfx + ((size_t)h * L_SEQ + b2i * 64 + 63) * 24;
    const float* S2p = kpfx + ((size_t)h * L_SEQ + b2i * 64 + rm1) * 24;
    float f1 = (b >= 1) ? 1.f : 0.f;
    float f2 = (b >= 2) ? 1.f : 0.f;
    float fr = (b >= 2 && r >= 1) ? 1.f : 0.f;
    float psc = 0.f, kcs = 0.f, bnd = 0.f;
#pragma unroll
    for (int m = 0; m < 24; ++m) {
      float qp = sQpF[r * 24 + m];
      float kc = kfc[m];
      psc += qp * kc;
      kcs += qp * kcx[m];
      bnd += qp * (kc + f1 * T1p[m] + f2 * T2p[m] - fr * S2p[m]);
    }
    float goc = kcs + psc;            // global_out_cumsum
    float gqk = SCALE_F * bnd;        // gqk_sum
    float se = sSum[r];
    float lse = __logf(se);           // qk_lse over band
    float gscale = qlog + stabk[h] - HLM_F;
    float gln = __logf(fmaxf(goc - gqk, 1e-24f)) + gscale;
    float mx2 = fmaxf(lse, gln), mn2 = fminf(lse, gln);
    float lognorm = mx2 + log1pf(__expf(mn2 - mx2));
    sGps[r] = __expf(gscale - lognorm);
    sRin[r] = 1.f / se;
  }
  __syncthreads();

  // ---- form W (bf16) into old K region ----
  float gpr[4], rin[4];
#pragma unroll
  for (int reg = 0; reg < 4; ++reg) {
    int rl = wv * 16 + g * 4 + reg;
    gpr[reg] = sGps[rl];
    rin[reg] = sRin[rl];
  }
#pragma unroll
  for (int nt = 0; nt < 12; ++nt) {
    int j = nt * 16 + ln;
#pragma unroll
    for (int reg = 0; reg < 4; ++reg) {
      int rl = wv * 16 + g * 4 + reg;
      bool causal = (j >= 128) && (j <= 128 + rl);
      bool bprev = (j >= rl) && (j < 128) && (j >= jmin);
      float coef = causal ? (1.f - SCALE_F) * gpr[reg] : (bprev ? -SCALE_F * gpr[reg] : 0.f);
      float wgt = eF[nt][reg] * rin[reg] + coef * pF[nt][reg];
      float wn = __shfl_xor(wgt, 1);
      if ((ln & 1) == 0) {
        *(unsigned*)(sKW + (rl * 384 + ((j * 2) ^ ((rl & 7) << 4)))) = pk2(wgt, wn);
      }
    }
  }
  __syncthreads();

  // ---- O1 = W * V (192-K), V^T tiles staged per 64 cols ----
  f32x4 oF[4];
#pragma unroll
  for (int dt = 0; dt < 4; ++dt) { f32x4 z = {0.f, 0.f, 0.f, 0.f}; oF[dt] = z; }
  for (int vt3 = 0; vt3 < 3; ++vt3) {
    int lt = b - 2 + vt3; lt = lt < 0 ? 0 : lt;
    for (int w = t; w < 2048; w += 256) {
      int d = w >> 5, jp = w & 31;
      *(unsigned*)(sQV + (d * 128 + ((jp * 4) ^ ((d & 7) << 4)))) = vtw[((size_t)h * NCH + lt) * 2048 + d * 32 + jp];
    }
    __syncthreads();
#pragma unroll
    for (int ks = 0; ks < 2; ++ks) {
      short8v aw = *(const short8v*)(sKW + (rA * 384 + ((vt3 * 128 + ks * 64 + g * 16) ^ ((rA & 7) << 4))));
#pragma unroll
      for (int dt = 0; dt < 4; ++dt) {
        int rB = dt * 16 + ln;
        short8v bv = *(const short8v*)(sQV + (rB * 128 + ((ks * 64 + g * 16) ^ ((rB & 7) << 4))));
        oF[dt] = __builtin_amdgcn_mfma_f32_16x16x32_bf16(aw, bv, oF[dt], 0, 0, 0);
      }
    }
    __syncthreads();
  }

  // ---- Og = q' * KVexcl ----
  for (int w = t; w < 1024; w += 256) {
    int d = w >> 4, mp = w & 15;
    *(unsigned*)(sKp + (d * 64 + ((mp * 4) ^ ((d & 3) << 4)))) = kvxt[((size_t)h * NCH + b) * 1024 + w];
  }
  __syncthreads();
  short8v aq = *(const short8v*)(sQp + (rA * 64 + ((g * 16) ^ ((rA & 3) << 4))));
  f32x4 ogF[4];
#pragma unroll
  for (int dt = 0; dt < 4; ++dt) {
    int rB = dt * 16 + ln;
    short8v bg = *(const short8v*)(sKp + (rB * 64 + ((g * 16) ^ ((rB & 3) << 4))));
    f32x4 z = {0.f, 0.f, 0.f, 0.f};
    ogF[dt] = __builtin_amdgcn_mfma_f32_16x16x32_bf16(aq, bg, z, 0, 0, 0);
  }

  // ---- epilogue: out = O1 + gps * Og ----
#pragma unroll
  for (int dt = 0; dt < 4; ++dt) {
    int d = dt * 16 + ln;
#pragma unroll
    for (int reg = 0; reg < 4; ++reg) {
      int rl = wv * 16 + g * 4 + reg;
      int l = b * 64 + rl;
      out[((size_t)l * NH + h) * DH + d] = oF[dt][reg] + gpr[reg] * ogF[dt][reg];
    }
  }
}

extern "C" void kernel_launch(void* const* d_in, const int* in_sizes, int n_in,
                              void* d_out, int out_size, void* d_ws, size_t ws_size,
                              hipStream_t stream)
{
  const float* qkv = (const float*)d_in[0];
  const float* proj = (const float*)d_in[1];
  float* out = (float*)d_out;
  char* ws = (char*)d_ws;

  float* kdash   = (float*)(ws + 0);           // 3145728
  float* qdash   = (float*)(ws + 3145728);     // 3145728
  float* knorm   = (float*)(ws + 6291456);     // 131072
  float* qnorm   = (float*)(ws + 6422528);     // 131072
  float* pmax    = (float*)(ws + 6553600);     // 2048
  float* stabk   = (float*)(ws + 6555648);     // 64
  unsigned* kpw  = (unsigned*)(ws + 6556672);  // 2097152 (bf16 [H][L][32])
  float* kpfx    = (float*)(ws + 8653824);     // 3145728
  unsigned* vtw  = (unsigned*)(ws + 11799552); // 4194304 (bf16 [H][32][64][64])
  float* kvs     = (float*)(ws + 15993856);    // 3145728
  unsigned* kvxt = (unsigned*)(ws + 19139584); // 2097152 (bf16 [H][32][64][32])
  float* kcumx   = (float*)(ws + 21236736);    // 49152   (ends at 21285888)

  k1_feat<<<dim3(32, 16), 256, 0, stream>>>(qkv, proj, kdash, knorm, qdash, qnorm, pmax);
  k2_stab<<<16, 64, 0, stream>>>(pmax, stabk);
  k3_kprime<<<dim3(32, 16), 256, 0, stream>>>(qkv, kdash, knorm, stabk, kpw, kpfx, kvs, vtw);
  k5_prefix<<<dim3(32, 16), 256, 0, stream>>>(kvs, kpfx, kvxt, kcumx);
  k6_attn<<<dim3(32, 16), 256, 0, stream>>>(qkv, kpw, kpfx, kcumx, vtw, kvxt, qdash, qnorm, stabk, out);
}

// Round 4
// 136.706 us; speedup vs baseline: 1.5463x; 1.0770x over previous
//
#include <hip/hip_runtime.h>
#include <hip/hip_bf16.h>

#define L_SEQ 2048
#define NH 16
#define DH 64
#define NM 24
#define NCH 32
#define SCALE_F 0.125f
#define EPS_F 1e-4f
#define DN_F 0.35355339059327373f      // sqrt(0.125)
#define HLM_F 1.5890269151739727f      // 0.5*log(24)

typedef __attribute__((ext_vector_type(8))) short short8v;   // 8 bf16 = 4 VGPR (MFMA A/B frag)
typedef __attribute__((ext_vector_type(4))) float f32x4;     // MFMA C/D frag

// round-to-nearest-even f32 -> bf16
__device__ __forceinline__ unsigned short f2bf(float x) {
  unsigned u = __float_as_uint(x);
  u += 0x7FFFu + ((u >> 16) & 1u);
  return (unsigned short)(u >> 16);
}
__device__ __forceinline__ unsigned pk2(float a, float b) {
  return (unsigned)f2bf(a) | ((unsigned)f2bf(b) << 16);
}

// ---------------- K1: f32 features: qdash/kdash (L,24), qnorm/knorm, per-chunk kdash max
// float4 LDS reads; sX/sP padded to 68 floats (272B rows, 16B aligned, conflict-spread)
__global__ __launch_bounds__(256) void k1_feat(
    const float* __restrict__ qkv, const float* __restrict__ proj,
    float* __restrict__ kdash, float* __restrict__ knorm,
    float* __restrict__ qdash, float* __restrict__ qnorm,
    float* __restrict__ pmax)
{
  __shared__ __attribute__((aligned(16))) float sP[24][68];
  __shared__ __attribute__((aligned(16))) float sX[64][68];
  __shared__ float sRed[256];
  const int c = blockIdx.x, h = blockIdx.y, t = threadIdx.x;
  for (int i = t; i < 24 * 64; i += 256) sP[i >> 6][i & 63] = proj[i];
  float lmax = -1e30f;
  const int r = t >> 2, mg = t & 3;
  for (int qk = 0; qk < 2; ++qk) {
    const int slot = qk ? 0 : 1;   // first K (slot1), then Q (slot0)
    __syncthreads();
    for (int i = t; i < 4096; i += 256) {
      int rr = i >> 6, d = i & 63;
      int l = c * 64 + rr;
      sX[rr][d] = qkv[(((size_t)l * 3 + slot) * NH + h) * DH + d];
    }
    __syncthreads();
    float acc[6] = {0.f, 0.f, 0.f, 0.f, 0.f, 0.f};
    float sq = 0.f;
    for (int d4 = 0; d4 < 16; ++d4) {
      float4 xv = *(const float4*)&sX[r][d4 * 4];
      sq += xv.x * xv.x; sq += xv.y * xv.y; sq += xv.z * xv.z; sq += xv.w * xv.w;
#pragma unroll
      for (int i = 0; i < 6; ++i) {
        float4 pv = *(const float4*)&sP[mg * 6 + i][d4 * 4];
        acc[i] += xv.x * pv.x; acc[i] += xv.y * pv.y;
        acc[i] += xv.z * pv.z; acc[i] += xv.w * pv.w;
      }
    }
    int l = c * 64 + r;
    float* dsh = qk ? qdash : kdash;
#pragma unroll
    for (int i = 0; i < 6; ++i) {
      float v = acc[i] * DN_F;
      dsh[((size_t)h * L_SEQ + l) * 24 + mg * 6 + i] = v;
      if (!qk) lmax = fmaxf(lmax, v);
    }
    if (mg == 0) (qk ? qnorm : knorm)[h * L_SEQ + l] = 0.5f * SCALE_F * sq;
  }
  sRed[t] = lmax;
  __syncthreads();
#pragma unroll
  for (int s = 128; s > 0; s >>= 1) {
    if (t < s) sRed[t] = fmaxf(sRed[t], sRed[t + s]);
    __syncthreads();
  }
  if (t == 0) pmax[h * 32 + c] = sRed[0];
}

// ---------------- K2: per-head stabilizer = max over chunks
__global__ void k2_stab(const float* __restrict__ pmax, float* __restrict__ stabk)
{
  int h = blockIdx.x, t = threadIdx.x;  // 64 threads
  float v = (t < 32) ? pmax[h * 32 + t] : -1e30f;
#pragma unroll
  for (int m = 16; m; m >>= 1) v = fmaxf(v, __shfl_xor(v, m));
  if (t == 0) stabk[h] = v;
}

// ---------------- K3: k' (bf16 padded to 32), in-chunk prefix kpfx (f32), chunk k'(x)v sums (f32),
//                   plus V -> blocked transposed bf16 vt[h][chunk][d][64 cols l]
__global__ __launch_bounds__(256) void k3_kprime(
    const float* __restrict__ qkv, const float* __restrict__ kdash,
    const float* __restrict__ knorm, const float* __restrict__ stabk,
    unsigned* __restrict__ kpw, float* __restrict__ kpfx, float* __restrict__ kvs,
    unsigned* __restrict__ vtw)
{
  __shared__ float sKp[64][25];
  __shared__ __attribute__((aligned(16))) float sV[64][68];
  const int c = blockIdx.x, h = blockIdx.y, t = threadIdx.x;
  const float stab = stabk[h];
  for (int i = t; i < 4096; i += 256) {
    int r = i >> 6, d = i & 63;
    int l = c * 64 + r;
    sV[r][d] = qkv[(((size_t)l * 3 + 2) * NH + h) * DH + d];
  }
  for (int i = t; i < 1536; i += 256) {
    int r = i / 24, m = i % 24;
    int l = c * 64 + r;
    sKp[r][m] = __expf(kdash[((size_t)h * L_SEQ + l) * 24 + m] - knorm[h * L_SEQ + l] - stab) + EPS_F;
  }
  __syncthreads();
  for (int w = t; w < 1024; w += 256) {   // write kp bf16, m padded to 32 with zeros
    int r = w >> 4, wo = w & 15;
    int l = c * 64 + r;
    float a = (wo < 12) ? sKp[r][2 * wo] : 0.f;
    float bb = (wo < 12) ? sKp[r][2 * wo + 1] : 0.f;
    kpw[((size_t)h * L_SEQ + l) * 16 + wo] = pk2(a, bb);
  }
  // V transpose to bf16 blocked layout
  for (int w = t; w < 2048; w += 256) {
    int d = w >> 5, lp = w & 31;
    vtw[((size_t)h * NCH + c) * 2048 + d * 32 + lp] = pk2(sV[2 * lp][d], sV[2 * lp + 1][d]);
  }
  // kvs[m][d] = sum_r kp[r][m] * v[r][d]; thread t<192 owns (m = t%24, d octet)
  if (t < 192) {
    const int m = t % 24, dO = (t / 24) * 8;
    float a0x = 0.f, a0y = 0.f, a0z = 0.f, a0w = 0.f;
    float a1x = 0.f, a1y = 0.f, a1z = 0.f, a1w = 0.f;
    for (int r2 = 0; r2 < 64; ++r2) {
      float kp = sKp[r2][m];
      float4 v0 = *(const float4*)&sV[r2][dO];
      float4 v1 = *(const float4*)&sV[r2][dO + 4];
      a0x += kp * v0.x; a0y += kp * v0.y; a0z += kp * v0.z; a0w += kp * v0.w;
      a1x += kp * v1.x; a1y += kp * v1.y; a1z += kp * v1.z; a1w += kp * v1.w;
    }
    float* dst = kvs + ((size_t)h * NCH + c) * 1536 + m * 64 + dO;
    float4 o0 = {a0x, a0y, a0z, a0w};
    float4 o1 = {a1x, a1y, a1z, a1w};
    *(float4*)dst = o0;
    *(float4*)(dst + 4) = o1;
  }
  if (t < 24) {
    float run = 0.f;
    for (int r2 = 0; r2 < 64; ++r2) {
      run += sKp[r2][t];
      kpfx[((size_t)h * L_SEQ + c * 64 + r2) * 24 + t] = run;
    }
  }
}

// ---------------- K6: fused banded + performer attention, one block per (h, 64-row chunk).
// Now also absorbs the former K5: exclusive chunk-prefix of kvs (-> sPfx -> sKp bf16)
// and kcum-excl (-> sKcx), computed pre-barrier where latency overlaps staging.
__global__ __launch_bounds__(256, 2) void k6_attn(
    const float* __restrict__ qkv, const unsigned* __restrict__ kpw,
    const float* __restrict__ kpfx, const float* __restrict__ kvs,
    const unsigned* __restrict__ vtw,
    const float* __restrict__ qdash, const float* __restrict__ qnorm,
    const float* __restrict__ stabk, float* __restrict__ out)
{
  __shared__ __attribute__((aligned(16))) char lds[62304];
  char* sKW = lds;                       // [192][64]b16 K tiles; later W [64][192]b16 (24576 B)
  char* sKp = lds + 24576;               // [192][32]b16 k'; later KVexcl^T [64][32]b16 (12288 B)
  char* sQV = lds + 36864;               // [64][64]b16 Q; later V^T tile (8192 B)
  char* sQp = lds + 45056;               // [64][32]b16 q' (4096 B)
  float* sQpF = (float*)(lds + 49152);   // [64][24] f32 q' for stats (6144 B)
  float* sSum = (float*)(lds + 55296);   // sumexp[64]
  float* sGps = sSum + 64;
  float* sRin = sGps + 64;
  float* sKcx = (float*)(lds + 56064);   // [24] kcum-excl (96 B)
  float* sPfx = (float*)(lds + 56160);   // [1536] f32 KVexcl (6144 B)

  const int b = blockIdx.x, h = blockIdx.y, t = threadIdx.x;
  const int wv = t >> 6, lane = t & 63, g = lane >> 4, ln = lane & 15;
  const int keybase = b * 64 - 128;
  const int jmin = (b >= 2) ? 0 : (128 - 64 * b);
  const int rA = wv * 16 + ln;   // A-frag row (query row owned by this wave's m-tile)

  // ---- stage K (192 rows, f32->bf16, XOR swizzled rows) ----
  for (int w = t; w < 6144; w += 256) {
    int r = w >> 5, dp = w & 31;
    int l = keybase + r; l = l < 0 ? 0 : l;
    const float* s = qkv + (((size_t)l * 3 + 1) * NH + h) * DH + dp * 2;
    *(unsigned*)(sKW + (r * 128 + (((dp * 4)) ^ ((r & 7) << 4)))) = pk2(s[0], s[1]);
  }
  // ---- stage Q ----
  for (int w = t; w < 2048; w += 256) {
    int r = w >> 5, dp = w & 31;
    int l = b * 64 + r;
    const float* s = qkv + (((size_t)l * 3 + 0) * NH + h) * DH + dp * 2;
    *(unsigned*)(sQV + (r * 128 + (((dp * 4)) ^ ((r & 7) << 4)))) = pk2(s[0], s[1]);
  }
  // ---- stage k' (bf16, already padded to 32) ----
  for (int w = t; w < 3072; w += 256) {
    int r = w >> 4, wo = w & 15;
    int l = keybase + r; l = l < 0 ? 0 : l;
    *(unsigned*)(sKp + (r * 64 + (((wo * 4)) ^ ((r & 3) << 4)))) = kpw[((size_t)h * L_SEQ + l) * 16 + wo];
  }
  // ---- folded K5: exclusive chunk-prefix of kvs (coalesced; overlaps staging latency) ----
  {
    float accp[6] = {0.f, 0.f, 0.f, 0.f, 0.f, 0.f};
    for (int bp = 0; bp < b; ++bp) {
      const float* src = kvs + ((size_t)h * NCH + bp) * 1536;
#pragma unroll
      for (int j = 0; j < 6; ++j) accp[j] += src[t + j * 256];
    }
#pragma unroll
    for (int j = 0; j < 6; ++j) sPfx[t + j * 256] = accp[j];
  }
  if (t < 24) {
    float runk = 0.f;
    for (int bp = 0; bp < b; ++bp)
      runk += kpfx[((size_t)h * L_SEQ + bp * 64 + 63) * 24 + t];
    sKcx[t] = runk;
  }
  // ---- q' per row (f32 stats copy + bf16 frag copy) ----
  float qlog = 0.f;
  if (t < 64) {
    int r = t, l = b * 64 + r;
    const float* qdp = qdash + ((size_t)h * L_SEQ + l) * 24;
    float qd[24], mx = -1e30f;
#pragma unroll
    for (int m = 0; m < 24; ++m) { qd[m] = qdp[m]; mx = fmaxf(mx, qd[m]); }
    float qpv[24];
#pragma unroll
    for (int m = 0; m < 24; ++m) { qpv[m] = __expf(qd[m] - mx) + EPS_F; sQpF[r * 24 + m] = qpv[m]; }
    qlog = mx - qnorm[h * L_SEQ + l] - HLM_F;
#pragma unroll
    for (int wo = 0; wo < 16; ++wo) {
      float a = (wo < 12) ? qpv[2 * wo] : 0.f;
      float bb = (wo < 12) ? qpv[2 * wo + 1] : 0.f;
      *(unsigned*)(sQp + (r * 64 + (((wo * 4)) ^ ((r & 3) << 4)))) = pk2(a, bb);
    }
  }
  __syncthreads();

  // ---- S = Q K^T (masked exp), wave-local row sums ----
  float eF[12][4];
  float rs[4] = {0.f, 0.f, 0.f, 0.f};
  short8v aS0 = *(const short8v*)(sQV + (rA * 128 + ((g * 16) ^ ((rA & 7) << 4))));
  short8v aS1 = *(const short8v*)(sQV + (rA * 128 + ((64 + g * 16) ^ ((rA & 7) << 4))));
#pragma unroll
  for (int nt = 0; nt < 12; ++nt) {
    int rB = nt * 16 + ln;
    short8v b0 = *(const short8v*)(sKW + (rB * 128 + ((g * 16) ^ ((rB & 7) << 4))));
    short8v b1 = *(const short8v*)(sKW + (rB * 128 + ((64 + g * 16) ^ ((rB & 7) << 4))));
    f32x4 acc = {0.f, 0.f, 0.f, 0.f};
    acc = __builtin_amdgcn_mfma_f32_16x16x32_bf16(aS0, b0, acc, 0, 0, 0);
    acc = __builtin_amdgcn_mfma_f32_16x16x32_bf16(aS1, b1, acc, 0, 0, 0);
    int j = nt * 16 + ln;
#pragma unroll
    for (int reg = 0; reg < 4; ++reg) {
      int rl = wv * 16 + g * 4 + reg;
      float e = 0.f;
      if (j >= rl && j <= rl + 128 && j >= jmin) e = __expf(SCALE_F * acc[reg]);
      eF[nt][reg] = e;
      rs[reg] += e;
    }
  }
#pragma unroll
  for (int reg = 0; reg < 4; ++reg) {
    float v = rs[reg];
    v += __shfl_xor(v, 1); v += __shfl_xor(v, 2);
    v += __shfl_xor(v, 4); v += __shfl_xor(v, 8);
    if (ln == 0) sSum[wv * 16 + g * 4 + reg] = v;
  }

  // ---- P = q' k'^T ----
  float pF[12][4];
  short8v aP = *(const short8v*)(sQp + (rA * 64 + ((g * 16) ^ ((rA & 3) << 4))));
#pragma unroll
  for (int nt = 0; nt < 12; ++nt) {
    int rB = nt * 16 + ln;
    short8v bp = *(const short8v*)(sKp + (rB * 64 + ((g * 16) ^ ((rB & 3) << 4))));
    f32x4 acc = {0.f, 0.f, 0.f, 0.f};
    acc = __builtin_amdgcn_mfma_f32_16x16x32_bf16(aP, bp, acc, 0, 0, 0);
#pragma unroll
    for (int reg = 0; reg < 4; ++reg) pF[nt][reg] = acc[reg];
  }
  __syncthreads();

  // ---- per-row stats (f32, via k' prefix sums) ----
  if (t < 64) {
    int r = t, l = b * 64 + r;
    const float* kfc = kpfx + ((size_t)h * L_SEQ + l) * 24;
    int b1i = (b >= 1) ? b - 1 : 0;
    int b2i = (b >= 2) ? b - 2 : 0;
    int rm1 = (r >= 1) ? r - 1 : 0;
    const float* T1p = kpfx + ((size_t)h * L_SEQ + b1i * 64 + 63) * 24;
    const float* T2p = kpfx + ((size_t)h * L_SEQ + b2i * 64 + 63) * 24;
    const float* S2p = kpfx + ((size_t)h * L_SEQ + b2i * 64 + rm1) * 24;
    float f1 = (b >= 1) ? 1.f : 0.f;
    float f2 = (b >= 2) ? 1.f : 0.f;
    float fr = (b >= 2 && r >= 1) ? 1.f : 0.f;
    float psc = 0.f, kcs = 0.f, bnd = 0.f;
#pragma unroll
    for (int m = 0; m < 24; ++m) {
      float qp = sQpF[r * 24 + m];
      float kc = kfc[m];
      psc += qp * kc;
      kcs += qp * sKcx[m];
      bnd += qp * (kc + f1 * T1p[m] + f2 * T2p[m] - fr * S2p[m]);
    }
    float goc = kcs + psc;            // global_out_cumsum
    float gqk = SCALE_F * bnd;        // gqk_sum
    float se = sSum[r];
    float lse = __logf(se);           // qk_lse over band
    float gscale = qlog + stabk[h] - HLM_F;
    float gln = __logf(fmaxf(goc - gqk, 1e-24f)) + gscale;
    float mx2 = fmaxf(lse, gln), mn2 = fminf(lse, gln);
    float lognorm = mx2 + log1pf(__expf(mn2 - mx2));
    sGps[r] = __expf(gscale - lognorm);
    sRin[r] = 1.f / se;
  }
  __syncthreads();

  // ---- form W (bf16) into old K region ----
  float gpr[4], rin[4];
#pragma unroll
  for (int reg = 0; reg < 4; ++reg) {
    int rl = wv * 16 + g * 4 + reg;
    gpr[reg] = sGps[rl];
    rin[reg] = sRin[rl];
  }
#pragma unroll
  for (int nt = 0; nt < 12; ++nt) {
    int j = nt * 16 + ln;
#pragma unroll
    for (int reg = 0; reg < 4; ++reg) {
      int rl = wv * 16 + g * 4 + reg;
      bool causal = (j >= 128) && (j <= 128 + rl);
      bool bprev = (j >= rl) && (j < 128) && (j >= jmin);
      float coef = causal ? (1.f - SCALE_F) * gpr[reg] : (bprev ? -SCALE_F * gpr[reg] : 0.f);
      float wgt = eF[nt][reg] * rin[reg] + coef * pF[nt][reg];
      float wn = __shfl_xor(wgt, 1);
      if ((ln & 1) == 0) {
        *(unsigned*)(sKW + (rl * 384 + ((j * 2) ^ ((rl & 7) << 4)))) = pk2(wgt, wn);
      }
    }
  }
  __syncthreads();

  // ---- pack KVexcl^T bf16 into sKp (from sPfx; sKp dead since P phase) ----
  for (int w = t; w < 1024; w += 256) {
    int d = w >> 4, mp = w & 15;
    int m0 = 2 * mp, m1 = m0 + 1;
    float a = (m0 < 24) ? sPfx[m0 * 64 + d] : 0.f;
    float bb = (m1 < 24) ? sPfx[m1 * 64 + d] : 0.f;
    *(unsigned*)(sKp + (d * 64 + ((mp * 4) ^ ((d & 3) << 4)))) = pk2(a, bb);
  }

  // ---- O1 = W * V (192-K), V^T tiles staged per 64 cols ----
  f32x4 oF[4];
#pragma unroll
  for (int dt = 0; dt < 4; ++dt) { f32x4 z = {0.f, 0.f, 0.f, 0.f}; oF[dt] = z; }
  for (int vt3 = 0; vt3 < 3; ++vt3) {
    int lt = b - 2 + vt3; lt = lt < 0 ? 0 : lt;
    for (int w = t; w < 2048; w += 256) {
      int d = w >> 5, jp = w & 31;
      *(unsigned*)(sQV + (d * 128 + ((jp * 4) ^ ((d & 7) << 4)))) = vtw[((size_t)h * NCH + lt) * 2048 + d * 32 + jp];
    }
    __syncthreads();
#pragma unroll
    for (int ks = 0; ks < 2; ++ks) {
      short8v aw = *(const short8v*)(sKW + (rA * 384 + ((vt3 * 128 + ks * 64 + g * 16) ^ ((rA & 7) << 4))));
#pragma unroll
      for (int dt = 0; dt < 4; ++dt) {
        int rB = dt * 16 + ln;
        short8v bv = *(const short8v*)(sQV + (rB * 128 + ((ks * 64 + g * 16) ^ ((rB & 7) << 4))));
        oF[dt] = __builtin_amdgcn_mfma_f32_16x16x32_bf16(aw, bv, oF[dt], 0, 0, 0);
      }
    }
    __syncthreads();
  }

  // ---- Og = q' * KVexcl (sKp packed earlier; visible via WV-loop barriers) ----
  short8v aq = *(const short8v*)(sQp + (rA * 64 + ((g * 16) ^ ((rA & 3) << 4))));
  f32x4 ogF[4];
#pragma unroll
  for (int dt = 0; dt < 4; ++dt) {
    int rB = dt * 16 + ln;
    short8v bg = *(const short8v*)(sKp + (rB * 64 + ((g * 16) ^ ((rB & 3) << 4))));
    f32x4 z = {0.f, 0.f, 0.f, 0.f};
    ogF[dt] = __builtin_amdgcn_mfma_f32_16x16x32_bf16(aq, bg, z, 0, 0, 0);
  }

  // ---- epilogue: out = O1 + gps * Og ----
#pragma unroll
  for (int dt = 0; dt < 4; ++dt) {
    int d = dt * 16 + ln;
#pragma unroll
    for (int reg = 0; reg < 4; ++reg) {
      int rl = wv * 16 + g * 4 + reg;
      int l = b * 64 + rl;
      out[((size_t)l * NH + h) * DH + d] = oF[dt][reg] + gpr[reg] * ogF[dt][reg];
    }
  }
}

extern "C" void kernel_launch(void* const* d_in, const int* in_sizes, int n_in,
                              void* d_out, int out_size, void* d_ws, size_t ws_size,
                              hipStream_t stream)
{
  const float* qkv = (const float*)d_in[0];
  const float* proj = (const float*)d_in[1];
  float* out = (float*)d_out;
  char* ws = (char*)d_ws;

  float* kdash   = (float*)(ws + 0);           // 3145728
  float* qdash   = (float*)(ws + 3145728);     // 3145728
  float* knorm   = (float*)(ws + 6291456);     // 131072
  float* qnorm   = (float*)(ws + 6422528);     // 131072
  float* pmax    = (float*)(ws + 6553600);     // 2048
  float* stabk   = (float*)(ws + 6555648);     // 64
  unsigned* kpw  = (unsigned*)(ws + 6556672);  // 2097152 (bf16 [H][L][32])
  float* kpfx    = (float*)(ws + 8653824);     // 3145728
  unsigned* vtw  = (unsigned*)(ws + 11799552); // 4194304 (bf16 [H][32][64][64])
  float* kvs     = (float*)(ws + 15993856);    // 3145728 (ends at 19139584)

  k1_feat<<<dim3(32, 16), 256, 0, stream>>>(qkv, proj, kdash, knorm, qdash, qnorm, pmax);
  k2_stab<<<16, 64, 0, stream>>>(pmax, stabk);
  k3_kprime<<<dim3(32, 16), 256, 0, stream>>>(qkv, kdash, knorm, stabk, kpw, kpfx, kvs, vtw);
  k6_attn<<<dim3(32, 16), 256, 0, stream>>>(qkv, kpw, kpfx, kvs, vtw, qdash, qnorm, stabk, out);
}

// Round 5
// 125.747 us; speedup vs baseline: 1.6811x; 1.0872x over previous
//
#include <hip/hip_runtime.h>
#include <hip/hip_bf16.h>

#define L_SEQ 2048
#define NH 16
#define DH 64
#define NM 24
#define NCH 32
#define SCALE_F 0.125f
#define EPS_F 1e-4f
#define DN_F 0.35355339059327373f      // sqrt(0.125)
#define HLM_F 1.5890269151739727f      // 0.5*log(24)

typedef __attribute__((ext_vector_type(8))) short short8v;   // 8 bf16 = 4 VGPR (MFMA A/B frag)
typedef __attribute__((ext_vector_type(4))) float f32x4;     // MFMA C/D frag

// round-to-nearest-even f32 -> bf16
__device__ __forceinline__ unsigned short f2bf(float x) {
  unsigned u = __float_as_uint(x);
  u += 0x7FFFu + ((u >> 16) & 1u);
  return (unsigned short)(u >> 16);
}
__device__ __forceinline__ unsigned pk2(float a, float b) {
  return (unsigned)f2bf(a) | ((unsigned)f2bf(b) << 16);
}
// stabilizer from pmax[h][0..31]: exact max, order-independent
__device__ __forceinline__ float stab_from_pmax(const float* __restrict__ pmax, int h, int t) {
  float v = pmax[h * 32 + (t & 31)];
  v = fmaxf(v, __shfl_xor(v, 1));  v = fmaxf(v, __shfl_xor(v, 2));
  v = fmaxf(v, __shfl_xor(v, 4));  v = fmaxf(v, __shfl_xor(v, 8));
  v = fmaxf(v, __shfl_xor(v, 16));
  return v;
}

// ---------------- K1: f32 features qdash/kdash (L,24), qnorm/knorm, per-chunk kdash max,
//                   plus bf16 pre-swizzled K/Q tiles (kbw/qbw [H][L][32 u32], word^((l&7)<<2))
__global__ __launch_bounds__(256) void k1_feat(
    const float* __restrict__ qkv, const float* __restrict__ proj,
    float* __restrict__ kdash, float* __restrict__ knorm,
    float* __restrict__ qdash, float* __restrict__ qnorm,
    float* __restrict__ pmax, unsigned* __restrict__ kbw, unsigned* __restrict__ qbw)
{
  __shared__ __attribute__((aligned(16))) float sP[24][68];
  __shared__ __attribute__((aligned(16))) float sX[64][68];
  __shared__ float sRed[256];
  const int c = blockIdx.x, h = blockIdx.y, t = threadIdx.x;
  for (int i = t; i < 24 * 64; i += 256) sP[i >> 6][i & 63] = proj[i];
  float lmax = -1e30f;
  const int r = t >> 2, mg = t & 3;
  for (int qk = 0; qk < 2; ++qk) {
    const int slot = qk ? 0 : 1;   // first K (slot1), then Q (slot0)
    __syncthreads();
    for (int i = t; i < 1024; i += 256) {
      int rr = i >> 4, d4 = (i & 15) * 4;
      int l = c * 64 + rr;
      *(float4*)&sX[rr][d4] = *(const float4*)(qkv + (((size_t)l * 3 + slot) * NH + h) * DH + d4);
    }
    __syncthreads();
    // emit bf16 pre-swizzled tile (consumed by k6 as pure uint4 copies)
    unsigned* dstw = qk ? qbw : kbw;
    for (int w = t; w < 2048; w += 256) {
      int rr = w >> 5, wo = w & 31;
      int l = c * 64 + rr;
      float2 xv = *(const float2*)&sX[rr][2 * wo];
      dstw[((size_t)h * L_SEQ + l) * 32 + (wo ^ ((rr & 7) << 2))] = pk2(xv.x, xv.y);
    }
    float acc[6] = {0.f, 0.f, 0.f, 0.f, 0.f, 0.f};
    float sq = 0.f;
    for (int d4 = 0; d4 < 16; ++d4) {
      float4 xv = *(const float4*)&sX[r][d4 * 4];
      sq += xv.x * xv.x; sq += xv.y * xv.y; sq += xv.z * xv.z; sq += xv.w * xv.w;
#pragma unroll
      for (int i = 0; i < 6; ++i) {
        float4 pv = *(const float4*)&sP[mg * 6 + i][d4 * 4];
        acc[i] += xv.x * pv.x; acc[i] += xv.y * pv.y;
        acc[i] += xv.z * pv.z; acc[i] += xv.w * pv.w;
      }
    }
    int l = c * 64 + r;
    float* dsh = qk ? qdash : kdash;
#pragma unroll
    for (int i = 0; i < 6; ++i) {
      float v = acc[i] * DN_F;
      dsh[((size_t)h * L_SEQ + l) * 24 + mg * 6 + i] = v;
      if (!qk) lmax = fmaxf(lmax, v);
    }
    if (mg == 0) (qk ? qnorm : knorm)[h * L_SEQ + l] = 0.5f * SCALE_F * sq;
  }
  sRed[t] = lmax;
  __syncthreads();
#pragma unroll
  for (int s = 128; s > 0; s >>= 1) {
    if (t < s) sRed[t] = fmaxf(sRed[t], sRed[t + s]);
    __syncthreads();
  }
  if (t == 0) pmax[h * 32 + c] = sRed[0];
}

// ---------------- K3: k' (bf16 padded 32, pre-swizzled), in-chunk prefix kpfx (f32),
//                   chunk k'(x)v sums kvs (f32), V^T bf16 pre-swizzled vtw
__global__ __launch_bounds__(256) void k3_kprime(
    const float* __restrict__ qkv, const float* __restrict__ kdash,
    const float* __restrict__ knorm, const float* __restrict__ pmax,
    unsigned* __restrict__ kpw, float* __restrict__ kpfx, float* __restrict__ kvs,
    unsigned* __restrict__ vtw)
{
  __shared__ float sKp[64][25];
  __shared__ __attribute__((aligned(16))) float sV[64][68];
  const int c = blockIdx.x, h = blockIdx.y, t = threadIdx.x;
  const float stab = stab_from_pmax(pmax, h, t);
  for (int i = t; i < 1024; i += 256) {
    int rr = i >> 4, d4 = (i & 15) * 4;
    int l = c * 64 + rr;
    *(float4*)&sV[rr][d4] = *(const float4*)(qkv + (((size_t)l * 3 + 2) * NH + h) * DH + d4);
  }
  for (int i = t; i < 1536; i += 256) {
    int r = i / 24, m = i % 24;
    int l = c * 64 + r;
    sKp[r][m] = __expf(kdash[((size_t)h * L_SEQ + l) * 24 + m] - knorm[h * L_SEQ + l] - stab) + EPS_F;
  }
  __syncthreads();
  for (int w = t; w < 1024; w += 256) {   // kp bf16, m padded to 32, pre-swizzled word^((l&3)<<2)
    int r = w >> 4, wo = w & 15;
    int l = c * 64 + r;
    float a = (wo < 12) ? sKp[r][2 * wo] : 0.f;
    float bb = (wo < 12) ? sKp[r][2 * wo + 1] : 0.f;
    kpw[((size_t)h * L_SEQ + l) * 16 + (wo ^ ((r & 3) << 2))] = pk2(a, bb);
  }
  // V transpose to bf16 blocked layout, pre-swizzled word^((d&7)<<2)
  for (int w = t; w < 2048; w += 256) {
    int d = w >> 5, jp = w & 31;
    vtw[((size_t)h * NCH + c) * 2048 + d * 32 + (jp ^ ((d & 7) << 2))] = pk2(sV[2 * jp][d], sV[2 * jp + 1][d]);
  }
  // kvs[m][d] = sum_r kp[r][m] * v[r][d]; thread t<192 owns (m = t%24, d octet)
  if (t < 192) {
    const int m = t % 24, dO = (t / 24) * 8;
    float a0x = 0.f, a0y = 0.f, a0z = 0.f, a0w = 0.f;
    float a1x = 0.f, a1y = 0.f, a1z = 0.f, a1w = 0.f;
    for (int r2 = 0; r2 < 64; ++r2) {
      float kp = sKp[r2][m];
      float4 v0 = *(const float4*)&sV[r2][dO];
      float4 v1 = *(const float4*)&sV[r2][dO + 4];
      a0x += kp * v0.x; a0y += kp * v0.y; a0z += kp * v0.z; a0w += kp * v0.w;
      a1x += kp * v1.x; a1y += kp * v1.y; a1z += kp * v1.z; a1w += kp * v1.w;
    }
    float* dst = kvs + ((size_t)h * NCH + c) * 1536 + m * 64 + dO;
    float4 o0 = {a0x, a0y, a0z, a0w};
    float4 o1 = {a1x, a1y, a1z, a1w};
    *(float4*)dst = o0;
    *(float4*)(dst + 4) = o1;
  }
  if (t < 24) {
    float run = 0.f;
    for (int r2 = 0; r2 < 64; ++r2) {
      run += sKp[r2][t];
      kpfx[((size_t)h * L_SEQ + c * 64 + r2) * 24 + t] = run;
    }
  }
}

// ---------------- K6: fused banded + performer attention, one block per (h, 64-row chunk).
// Staging is now pure uint4 copies of pre-swizzled bf16 (no qkv access, no conversion).
__global__ __launch_bounds__(256, 2) void k6_attn(
    const unsigned* __restrict__ kpw, const float* __restrict__ kpfx,
    const float* __restrict__ kvs, const unsigned* __restrict__ vtw,
    const float* __restrict__ qdash, const float* __restrict__ qnorm,
    const float* __restrict__ pmax, const unsigned* __restrict__ kbw,
    const unsigned* __restrict__ qbw, float* __restrict__ out)
{
  __shared__ __attribute__((aligned(16))) char lds[62304];
  char* sKW = lds;                       // [192][64]b16 K tiles; later W [64][192]b16 (24576 B)
  char* sKp = lds + 24576;               // [192][32]b16 k'; later KVexcl^T [64][32]b16 (12288 B)
  char* sQV = lds + 36864;               // [64][64]b16 Q; later V^T tile (8192 B)
  char* sQp = lds + 45056;               // [64][32]b16 q' (4096 B)
  float* sQpF = (float*)(lds + 49152);   // [64][24] f32 q' for stats (6144 B)
  float* sSum = (float*)(lds + 55296);   // sumexp[64]
  float* sGps = sSum + 64;
  float* sRin = sGps + 64;
  float* sKcx = (float*)(lds + 56064);   // [24] kcum-excl (96 B)
  float* sPfx = (float*)(lds + 56160);   // [1536] f32 KVexcl (6144 B)

  const int b = blockIdx.x, h = blockIdx.y, t = threadIdx.x;
  const int wv = t >> 6, lane = t & 63, g = lane >> 4, ln = lane & 15;
  const int keybase = b * 64 - 128;
  const int jmin = (b >= 2) ? 0 : (128 - 64 * b);
  const int rA = wv * 16 + ln;   // A-frag row (query row owned by this wave's m-tile)

  // ---- stage K (192 rows x 128B, pre-swizzled: pure linear uint4 copy) ----
  for (int w = t; w < 1536; w += 256) {
    int r = w >> 3, q4 = w & 7;
    int l = keybase + r; l = l < 0 ? 0 : l;
    *(uint4*)(sKW + r * 128 + q4 * 16) = *(const uint4*)(kbw + ((size_t)h * L_SEQ + l) * 32 + q4 * 4);
  }
  // ---- stage Q (64 rows x 128B) ----
  for (int w = t; w < 512; w += 256) {
    int r = w >> 3, q4 = w & 7;
    int l = b * 64 + r;
    *(uint4*)(sQV + r * 128 + q4 * 16) = *(const uint4*)(qbw + ((size_t)h * L_SEQ + l) * 32 + q4 * 4);
  }
  // ---- stage k' (192 rows x 64B) ----
  for (int w = t; w < 768; w += 256) {
    int r = w >> 2, q4 = w & 3;
    int l = keybase + r; l = l < 0 ? 0 : l;
    *(uint4*)(sKp + r * 64 + q4 * 16) = *(const uint4*)(kpw + ((size_t)h * L_SEQ + l) * 16 + q4 * 4);
  }
  const float stab = stab_from_pmax(pmax, h, t);
  // ---- exclusive chunk-prefix of kvs (coalesced; overlaps staging latency) ----
  {
    float accp[6] = {0.f, 0.f, 0.f, 0.f, 0.f, 0.f};
    for (int bp = 0; bp < b; ++bp) {
      const float* src = kvs + ((size_t)h * NCH + bp) * 1536;
#pragma unroll
      for (int j = 0; j < 6; ++j) accp[j] += src[t + j * 256];
    }
#pragma unroll
    for (int j = 0; j < 6; ++j) sPfx[t + j * 256] = accp[j];
  }
  if (t < 24) {
    float runk = 0.f;
    for (int bp = 0; bp < b; ++bp)
      runk += kpfx[((size_t)h * L_SEQ + bp * 64 + 63) * 24 + t];
    sKcx[t] = runk;
  }
  // ---- q' per row (f32 stats copy + bf16 frag copy) ----
  float qlog = 0.f;
  if (t < 64) {
    int r = t, l = b * 64 + r;
    const float* qdp = qdash + ((size_t)h * L_SEQ + l) * 24;
    float qd[24], mx = -1e30f;
#pragma unroll
    for (int m = 0; m < 24; ++m) { qd[m] = qdp[m]; mx = fmaxf(mx, qd[m]); }
    float qpv[24];
#pragma unroll
    for (int m = 0; m < 24; ++m) { qpv[m] = __expf(qd[m] - mx) + EPS_F; sQpF[r * 24 + m] = qpv[m]; }
    qlog = mx - qnorm[h * L_SEQ + l] - HLM_F;
#pragma unroll
    for (int wo = 0; wo < 16; ++wo) {
      float a = (wo < 12) ? qpv[2 * wo] : 0.f;
      float bb = (wo < 12) ? qpv[2 * wo + 1] : 0.f;
      *(unsigned*)(sQp + (r * 64 + (((wo * 4)) ^ ((r & 3) << 4)))) = pk2(a, bb);
    }
  }
  __syncthreads();

  // ---- S = Q K^T (masked exp), wave-local row sums ----
  float eF[12][4];
  float rs[4] = {0.f, 0.f, 0.f, 0.f};
  short8v aS0 = *(const short8v*)(sQV + (rA * 128 + ((g * 16) ^ ((rA & 7) << 4))));
  short8v aS1 = *(const short8v*)(sQV + (rA * 128 + ((64 + g * 16) ^ ((rA & 7) << 4))));
#pragma unroll
  for (int nt = 0; nt < 12; ++nt) {
    int rB = nt * 16 + ln;
    short8v b0 = *(const short8v*)(sKW + (rB * 128 + ((g * 16) ^ ((rB & 7) << 4))));
    short8v b1 = *(const short8v*)(sKW + (rB * 128 + ((64 + g * 16) ^ ((rB & 7) << 4))));
    f32x4 acc = {0.f, 0.f, 0.f, 0.f};
    acc = __builtin_amdgcn_mfma_f32_16x16x32_bf16(aS0, b0, acc, 0, 0, 0);
    acc = __builtin_amdgcn_mfma_f32_16x16x32_bf16(aS1, b1, acc, 0, 0, 0);
    int j = nt * 16 + ln;
#pragma unroll
    for (int reg = 0; reg < 4; ++reg) {
      int rl = wv * 16 + g * 4 + reg;
      float e = 0.f;
      if (j >= rl && j <= rl + 128 && j >= jmin) e = __expf(SCALE_F * acc[reg]);
      eF[nt][reg] = e;
      rs[reg] += e;
    }
  }
#pragma unroll
  for (int reg = 0; reg < 4; ++reg) {
    float v = rs[reg];
    v += __shfl_xor(v, 1); v += __shfl_xor(v, 2);
    v += __shfl_xor(v, 4); v += __shfl_xor(v, 8);
    if (ln == 0) sSum[wv * 16 + g * 4 + reg] = v;
  }

  // ---- P = q' k'^T ----
  float pF[12][4];
  short8v aP = *(const short8v*)(sQp + (rA * 64 + ((g * 16) ^ ((rA & 3) << 4))));
#pragma unroll
  for (int nt = 0; nt < 12; ++nt) {
    int rB = nt * 16 + ln;
    short8v bp = *(const short8v*)(sKp + (rB * 64 + ((g * 16) ^ ((rB & 3) << 4))));
    f32x4 acc = {0.f, 0.f, 0.f, 0.f};
    acc = __builtin_amdgcn_mfma_f32_16x16x32_bf16(aP, bp, acc, 0, 0, 0);
#pragma unroll
    for (int reg = 0; reg < 4; ++reg) pF[nt][reg] = acc[reg];
  }
  __syncthreads();

  // ---- per-row stats (f32, via k' prefix sums) ----
  if (t < 64) {
    int r = t, l = b * 64 + r;
    const float* kfc = kpfx + ((size_t)h * L_SEQ + l) * 24;
    int b1i = (b >= 1) ? b - 1 : 0;
    int b2i = (b >= 2) ? b - 2 : 0;
    int rm1 = (r >= 1) ? r - 1 : 0;
    const float* T1p = kpfx + ((size_t)h * L_SEQ + b1i * 64 + 63) * 24;
    const float* T2p = kpfx + ((size_t)h * L_SEQ + b2i * 64 + 63) * 24;
    const float* S2p = kpfx + ((size_t)h * L_SEQ + b2i * 64 + rm1) * 24;
    float f1 = (b >= 1) ? 1.f : 0.f;
    float f2 = (b >= 2) ? 1.f : 0.f;
    float fr = (b >= 2 && r >= 1) ? 1.f : 0.f;
    float psc = 0.f, kcs = 0.f, bnd = 0.f;
#pragma unroll
    for (int m = 0; m < 24; ++m) {
      float qp = sQpF[r * 24 + m];
      float kc = kfc[m];
      psc += qp * kc;
      kcs += qp * sKcx[m];
      bnd += qp * (kc + f1 * T1p[m] + f2 * T2p[m] - fr * S2p[m]);
    }
    float goc = kcs + psc;            // global_out_cumsum
    float gqk = SCALE_F * bnd;        // gqk_sum
    float se = sSum[r];
    float lse = __logf(se);           // qk_lse over band
    float gscale = qlog + stab - HLM_F;
    float gln = __logf(fmaxf(goc - gqk, 1e-24f)) + gscale;
    float mx2 = fmaxf(lse, gln), mn2 = fminf(lse, gln);
    float lognorm = mx2 + log1pf(__expf(mn2 - mx2));
    sGps[r] = __expf(gscale - lognorm);
    sRin[r] = 1.f / se;
  }
  __syncthreads();

  // ---- form W (bf16) into old K region ----
  float gpr[4], rin[4];
#pragma unroll
  for (int reg = 0; reg < 4; ++reg) {
    int rl = wv * 16 + g * 4 + reg;
    gpr[reg] = sGps[rl];
    rin[reg] = sRin[rl];
  }
#pragma unroll
  for (int nt = 0; nt < 12; ++nt) {
    int j = nt * 16 + ln;
#pragma unroll
    for (int reg = 0; reg < 4; ++reg) {
      int rl = wv * 16 + g * 4 + reg;
      bool causal = (j >= 128) && (j <= 128 + rl);
      bool bprev = (j >= rl) && (j < 128) && (j >= jmin);
      float coef = causal ? (1.f - SCALE_F) * gpr[reg] : (bprev ? -SCALE_F * gpr[reg] : 0.f);
      float wgt = eF[nt][reg] * rin[reg] + coef * pF[nt][reg];
      float wn = __shfl_xor(wgt, 1);
      if ((ln & 1) == 0) {
        *(unsigned*)(sKW + (rl * 384 + ((j * 2) ^ ((rl & 7) << 4)))) = pk2(wgt, wn);
      }
    }
  }
  __syncthreads();

  // ---- pack KVexcl^T bf16 into sKp (from sPfx; sKp dead since P phase) ----
  for (int w = t; w < 1024; w += 256) {
    int d = w >> 4, mp = w & 15;
    int m0 = 2 * mp, m1 = m0 + 1;
    float a = (m0 < 24) ? sPfx[m0 * 64 + d] : 0.f;
    float bb = (m1 < 24) ? sPfx[m1 * 64 + d] : 0.f;
    *(unsigned*)(sKp + (d * 64 + ((mp * 4) ^ ((d & 3) << 4)))) = pk2(a, bb);
  }

  // ---- O1 = W * V (192-K), V^T tiles staged per 64 cols (pre-swizzled, linear copy) ----
  f32x4 oF[4];
#pragma unroll
  for (int dt = 0; dt < 4; ++dt) { f32x4 z = {0.f, 0.f, 0.f, 0.f}; oF[dt] = z; }
  for (int vt3 = 0; vt3 < 3; ++vt3) {
    int lt = b - 2 + vt3; lt = lt < 0 ? 0 : lt;
    for (int w = t; w < 512; w += 256) {
      *(uint4*)(sQV + w * 16) = *(const uint4*)(vtw + ((size_t)h * NCH + lt) * 2048 + w * 4);
    }
    __syncthreads();
#pragma unroll
    for (int ks = 0; ks < 2; ++ks) {
      short8v aw = *(const short8v*)(sKW + (rA * 384 + ((vt3 * 128 + ks * 64 + g * 16) ^ ((rA & 7) << 4))));
#pragma unroll
      for (int dt = 0; dt < 4; ++dt) {
        int rB = dt * 16 + ln;
        short8v bv = *(const short8v*)(sQV + (rB * 128 + ((ks * 64 + g * 16) ^ ((rB & 7) << 4))));
        oF[dt] = __builtin_amdgcn_mfma_f32_16x16x32_bf16(aw, bv, oF[dt], 0, 0, 0);
      }
    }
    __syncthreads();
  }

  // ---- Og = q' * KVexcl (sKp packed earlier; visible via WV-loop barriers) ----
  short8v aq = *(const short8v*)(sQp + (rA * 64 + ((g * 16) ^ ((rA & 3) << 4))));
  f32x4 ogF[4];
#pragma unroll
  for (int dt = 0; dt < 4; ++dt) {
    int rB = dt * 16 + ln;
    short8v bg = *(const short8v*)(sKp + (rB * 64 + ((g * 16) ^ ((rB & 3) << 4))));
    f32x4 z = {0.f, 0.f, 0.f, 0.f};
    ogF[dt] = __builtin_amdgcn_mfma_f32_16x16x32_bf16(aq, bg, z, 0, 0, 0);
  }

  // ---- epilogue: out = O1 + gps * Og ----
#pragma unroll
  for (int dt = 0; dt < 4; ++dt) {
    int d = dt * 16 + ln;
#pragma unroll
    for (int reg = 0; reg < 4; ++reg) {
      int rl = wv * 16 + g * 4 + reg;
      int l = b * 64 + rl;
      out[((size_t)l * NH + h) * DH + d] = oF[dt][reg] + gpr[reg] * ogF[dt][reg];
    }
  }
}

extern "C" void kernel_launch(void* const* d_in, const int* in_sizes, int n_in,
                              void* d_out, int out_size, void* d_ws, size_t ws_size,
                              hipStream_t stream)
{
  const float* qkv = (const float*)d_in[0];
  const float* proj = (const float*)d_in[1];
  float* out = (float*)d_out;
  char* ws = (char*)d_ws;

  float* kdash   = (float*)(ws + 0);           // 3145728
  float* qdash   = (float*)(ws + 3145728);     // 3145728
  float* knorm   = (float*)(ws + 6291456);     // 131072
  float* qnorm   = (float*)(ws + 6422528);     // 131072
  float* pmax    = (float*)(ws + 6553600);     // 2048
  unsigned* kbw  = (unsigned*)(ws + 6555648);  // 4194304 (bf16 K pre-swizzled [H][L][32])
  unsigned* qbw  = (unsigned*)(ws + 10749952); // 4194304 (bf16 Q pre-swizzled [H][L][32])
  unsigned* kpw  = (unsigned*)(ws + 14944256); // 2097152 (bf16 k' pre-swizzled [H][L][16])
  float* kpfx    = (float*)(ws + 17041408);    // 3145728
  unsigned* vtw  = (unsigned*)(ws + 20187136); // 4194304 (bf16 V^T pre-swizzled [H][32][64][32])
  float* kvs     = (float*)(ws + 24381440);    // 3145728 (ends at 27527168)

  k1_feat<<<dim3(32, 16), 256, 0, stream>>>(qkv, proj, kdash, knorm, qdash, qnorm, pmax, kbw, qbw);
  k3_kprime<<<dim3(32, 16), 256, 0, stream>>>(qkv, kdash, knorm, pmax, kpw, kpfx, kvs, vtw);
  k6_attn<<<dim3(32, 16), 256, 0, stream>>>(kpw, kpfx, kvs, vtw, qdash, qnorm, pmax, kbw, qbw, out);
}